// Round 23
// baseline (109.388 us; speedup 1.0000x reference)
//
#include <hip/hip_runtime.h>

// MCA linear attention. B=8, C=64, H=W=160, P=8 heads, d=8, N=25600.
// MFMA on f16 split pairs (fp32-accurate). R21 + (1) k3 norm folded into
// phase B (lane already reads its head's 8 q-rows for the B-frag) and
// (2) s_setprio around MFMA clusters. pkrtz dropped (type-system fight).
#define NPIX  25600
#define NB    8
#define NCH   200    // pixel chunks per batch (128 px each)
#define KPX   128
#define EPSV  1e-6f

// workspace layout (float offsets)
#define WS_WQM   0        // Wq A-frags: 16 frags x 64 lanes x 8 f16
#define WS_BQM   4096     // [64 row] bias
#define WS_WKVM  4160     // Wkv A-frags: 32 frags x 512 f16-pairs
#define WS_BKVM  12352    // [8 mt][16 row] bias
#define WS_KSE   12480    // [8 b][8 p][8 m] (+eps)
#define WS_PART  12992    // [64 bh][200 ch][72]
#define WS_GM    934592   // G A-frags: 8 b x 16 frags x 512 f16

typedef __attribute__((ext_vector_type(8))) _Float16 half8v;
typedef __attribute__((ext_vector_type(4))) float f32x4v;

__device__ __forceinline__ void split_h(float x, _Float16& hi, _Float16& lo) {
  hi = (_Float16)x;                  // v_cvt_f16_f32 (RNE)
  lo = (_Float16)(x - (float)hi);    // residual, fp32-equivalent pair
}
__device__ __forceinline__ float softplus_(float x) {
  return (x > 20.0f) ? x : __logf(1.0f + __expf(x));
}

// ---------------- kernel 0: pack weight MFMA fragments (f16 pairs) ---------
__global__ void k0_pack(const float* __restrict__ wq_high, const float* __restrict__ bq_high,
                        const float* __restrict__ wq_low,  const float* __restrict__ bq_low,
                        const float* __restrict__ wk, const float* __restrict__ bk,
                        const float* __restrict__ wv, const float* __restrict__ bv,
                        float* __restrict__ ws) {
  const int tid = threadIdx.x;
  _Float16* wqm = (_Float16*)(ws + WS_WQM);
  for (int e = tid; e < 8192; e += 256) {
    int j = e & 7, l = (e >> 3) & 63, frag = e >> 9;
    int sp = frag & 1, ks = (frag >> 1) & 1, mt = frag >> 2;
    int row = mt * 16 + (l & 15), c = ks * 32 + (l >> 4) * 8 + j;
    int head = row >> 3, m = row & 7;
    float v = (head < 4) ? wq_high[(head * 8 + m) * 64 + c]
                         : wq_low[((head - 4) * 8 + m) * 64 + c];
    _Float16 hi, lo; split_h(v, hi, lo);
    wqm[e] = (sp == 0) ? hi : lo;
  }
  for (int e = tid; e < 64; e += 256) {
    int head = e >> 3, m = e & 7;
    ws[WS_BQM + e] = (head < 4) ? bq_high[head * 8 + m] : bq_low[(head - 4) * 8 + m];
  }
  _Float16* wmp = (_Float16*)(ws + WS_WKVM);
  for (int e = tid; e < 16384; e += 256) {
    int j = e & 7, l = (e >> 3) & 63, frag = e >> 9;
    int sp = frag & 1, ks = (frag >> 1) & 1, mt = frag >> 2;
    int row = l & 15, k32 = (l >> 4) * 8 + j, c = ks * 32 + k32;
    int head = (mt & 3) * 2 + (row >> 3), m = row & 7;
    float wv_ = (mt < 4) ? wk[(head * 8 + m) * 64 + c] : wv[(head * 8 + m) * 64 + c];
    _Float16 hi, lo; split_h(wv_, hi, lo);
    wmp[e] = (sp == 0) ? hi : lo;
  }
  for (int e = tid; e < 128; e += 256) {
    int mt = e >> 4, row = e & 15;
    int head = (mt & 3) * 2 + (row >> 3), m = row & 7;
    ws[WS_BKVM + e] = (mt < 4) ? bk[head * 8 + m] : bv[head * 8 + m];
  }
}

// ---------------- kernel 1: MFMA k,v + attn partials ----------------
// 512 thr = 8 waves; wave w owns px strip [16w,16w+16). GEMM1 -> split f16
// hi/lo LDS planes (64KB, 16B-unit XOR swizzle). GEMM2 reads frags directly.
__global__ __attribute__((amdgpu_waves_per_eu(1, 8)))
void k1_kv(const float* __restrict__ low,
           const float* __restrict__ ws,
           float* __restrict__ part) {
  const int b = blockIdx.y, chunk = blockIdx.x;
  const int tid = threadIdx.x, lane = tid & 63;
  const int w = __builtin_amdgcn_readfirstlane(tid >> 6);
  const int l15 = lane & 15, lg = lane >> 4;
  __shared__ _Float16 kvP[2][16384];             // hi/lo planes, [128r][128px]
  const float* lowb = low + (size_t)b * 64 * NPIX + chunk * KPX;
  // ---- X B-frags (f16 split) ----
  half8v xhi[2], xlo[2];
#pragma unroll
  for (int ks = 0; ks < 2; ks++) {
    const float* xp = lowb + (size_t)(ks * 32 + lg * 8) * NPIX + w * 16 + l15;
    float xs[8];
#pragma unroll
    for (int j = 0; j < 8; j++) xs[j] = xp[(size_t)j * NPIX];
#pragma unroll
    for (int j = 0; j < 8; j++) { _Float16 h, l; split_h(xs[j], h, l); xhi[ks][j] = h; xlo[ks][j] = l; }
  }
  const _Float16* wm = (const _Float16*)(ws + WS_WKVM);
  const float* bm = ws + WS_BKVM;
  // ---- GEMM1 ----
#pragma unroll
  for (int mt = 0; mt < 8; mt++) {
    f32x4v a0 = {0.f, 0.f, 0.f, 0.f};
    __builtin_amdgcn_s_setprio(1);
#pragma unroll
    for (int ks = 0; ks < 2; ks++) {
      half8v whi = *(const half8v*)(wm + (((mt * 4 + ks * 2 + 0) * 64) + lane) * 8);
      half8v wlo = *(const half8v*)(wm + (((mt * 4 + ks * 2 + 1) * 64) + lane) * 8);
      a0 = __builtin_amdgcn_mfma_f32_16x16x32_f16(whi, xhi[ks], a0, 0, 0, 0);
      a0 = __builtin_amdgcn_mfma_f32_16x16x32_f16(whi, xlo[ks], a0, 0, 0, 0);
      a0 = __builtin_amdgcn_mfma_f32_16x16x32_f16(wlo, xhi[ks], a0, 0, 0, 0);
    }
    __builtin_amdgcn_s_setprio(0);
#pragma unroll
    for (int r = 0; r < 4; r++) {
      const int row = mt * 16 + lg * 4 + r;
      float v0 = a0[r] + bm[row];
      if (mt < 4) v0 = softplus_(v0);
      const int px = w * 16 + l15;
      const int idx = row * 128 + ((((px >> 3) ^ (row & 7)) << 3) | (px & 7));
      _Float16 hi, lo; split_h(v0, hi, lo);
      kvP[0][idx] = hi;
      kvP[1][idx] = lo;
    }
  }
  __syncthreads();
  // ---- GEMM2: wave w -> head w; frags read directly from planes ----
  const int col = l15;
  const int h = w;
  f32x4v acc = {0.f, 0.f, 0.f, 0.f};
  const int arow = h * 8 + (l15 & 7);
  const int brow = 64 + h * 8 + (col < 8 ? col : 0);
#pragma unroll
  for (int ks = 0; ks < 4; ks++) {
    const int unitA = (((ks * 4 + lg) ^ (arow & 7)) << 3);
    const int unitB = (((ks * 4 + lg) ^ (brow & 7)) << 3);
    half8v ahi = *(const half8v*)&kvP[0][arow * 128 + unitA];
    half8v alo = *(const half8v*)&kvP[1][arow * 128 + unitA];
    half8v bhi = *(const half8v*)&kvP[0][brow * 128 + unitB];
    half8v blo = *(const half8v*)&kvP[1][brow * 128 + unitB];
    if (col >= 8) {
      const _Float16 fh = (col == 8) ? (_Float16)1.0f : (_Float16)0.0f;
#pragma unroll
      for (int j = 0; j < 8; j++) { bhi[j] = fh; blo[j] = (_Float16)0.0f; }
    }
    __builtin_amdgcn_s_setprio(1);
    acc = __builtin_amdgcn_mfma_f32_16x16x32_f16(ahi, bhi, acc, 0, 0, 0);
    acc = __builtin_amdgcn_mfma_f32_16x16x32_f16(ahi, blo, acc, 0, 0, 0);
    acc = __builtin_amdgcn_mfma_f32_16x16x32_f16(alo, bhi, acc, 0, 0, 0);
    __builtin_amdgcn_s_setprio(0);
  }
  if (lane < 32 && col <= 8) {
    float* pb = part + ((size_t)(b * 8 + h) * NCH + chunk) * 72;
#pragma unroll
    for (int r = 0; r < 4; r++) {
      const int rr = lg * 4 + r;
      if (col < 8) pb[rr * 8 + col] = acc[r];
      else         pb[64 + rr] = acc[r];
    }
  }
}

// ---------------- kernel 2: reduce partials, ksumE, G f16 frags ------------
__global__ void k2_g(const float* __restrict__ part, const float* __restrict__ wo,
                     float* __restrict__ ws) {
  const int b = blockIdx.x >> 3, p = blockIdx.x & 7;
  const int tid = threadIdx.x, lane = tid & 63, sub = tid >> 6;
  __shared__ float red[4][72];
  __shared__ float attnL[72];
  const float* src = part + (size_t)(b * 8 + p) * NCH * 72;
  float s0 = 0.0f, s1 = 0.0f;
  for (int ch = sub * (NCH / 4); ch < (sub + 1) * (NCH / 4); ch++) {
    s0 += src[ch * 72 + lane];
    if (lane < 8) s1 += src[ch * 72 + 64 + lane];
  }
  red[sub][lane] = s0;
  if (lane < 8) red[sub][64 + lane] = s1;
  __syncthreads();
  if (tid < 72) attnL[tid] = (red[0][tid] + red[1][tid]) + (red[2][tid] + red[3][tid]);
  __syncthreads();
  if (tid >= 64) {
    if (tid < 72) ws[WS_KSE + (b * 8 + p) * 8 + (tid - 64)] = attnL[tid] + EPSV;
    return;
  }
  const int o = tid;
  float wrow[8];
#pragma unroll
  for (int c = 0; c < 8; c++) wrow[c] = wo[o * 64 + p * 8 + c];
  _Float16* gm = (_Float16*)(ws + WS_GM) + (size_t)b * 8192;
  const int mt2 = o >> 4, lane_ = (p & 3) * 16 + (o & 15), ks = p >> 2;
  half8v hi8, lo8;
#pragma unroll
  for (int m = 0; m < 8; m++) {
    float g = 0.0f;
#pragma unroll
    for (int c = 0; c < 8; c++) g = fmaf(attnL[m * 8 + c], wrow[c], g);
    _Float16 hi, lo; split_h(g, hi, lo);
    hi8[m] = hi; lo8[m] = lo;
  }
  *(half8v*)(gm + (size_t)((mt2 * 4 + ks * 2 + 0) * 64 + lane_) * 8) = hi8;
  *(half8v*)(gm + (size_t)((mt2 * 4 + ks * 2 + 1) * 64 + lane_) * 8) = lo8;
}

// ---------------- kernel 3: MFMA q -> fused norm+out-projection ------------
// 512 thr = 8 waves, strip [16w,16w+16). Phase A -> fp32 qL (32KB swizzled).
// Phase B: lane reads head (ks*4+lg)'s 8 q-rows at its px (needed for the
// B-frag anyway) -> computes s, rn INLINE (norm phase + rnL + one barrier
// deleted). qsn scaled x4096 to dodge f16 subnormals; unscaled in epilogue.
__global__ __attribute__((amdgpu_waves_per_eu(1, 8)))
void k3_main(const float* __restrict__ high,
             const float* __restrict__ low,
             const float* __restrict__ ws,
             const float* __restrict__ bo,
             float* __restrict__ out) {
  const int b = blockIdx.y, chunk = blockIdx.x;
  const int tid = threadIdx.x, lane = tid & 63;
  const int w = __builtin_amdgcn_readfirstlane(tid >> 6);
  const int l15 = lane & 15, lg = lane >> 4;
  __shared__ float qL[8192];                     // [64 row][128 px] swizzled
  const float* highb = high + (size_t)b * 64 * NPIX + chunk * KPX;
  const float* lowb  = low  + (size_t)b * 64 * NPIX + chunk * KPX;
  // ---- X B-frags (both sources, f16 split) ----
  half8v xhi[2][2], xlo[2][2];                   // [src][ks]
#pragma unroll
  for (int s = 0; s < 2; s++) {
    const float* srcb = (s == 0) ? highb : lowb;
#pragma unroll
    for (int ks = 0; ks < 2; ks++) {
      const float* xp = srcb + (size_t)(ks * 32 + lg * 8) * NPIX + w * 16 + l15;
      float xs[8];
#pragma unroll
      for (int j = 0; j < 8; j++) xs[j] = xp[(size_t)j * NPIX];
#pragma unroll
      for (int j = 0; j < 8; j++) { _Float16 h, l; split_h(xs[j], h, l); xhi[s][ks][j] = h; xlo[s][ks][j] = l; }
    }
  }
  const _Float16* wqm = (const _Float16*)(ws + WS_WQM);
  const float* bqm = ws + WS_BQM;
  // ---- phase A ----
#pragma unroll
  for (int mt = 0; mt < 4; mt++) {
    const int s = mt >> 1;
    f32x4v a0 = {0.f, 0.f, 0.f, 0.f};
    __builtin_amdgcn_s_setprio(1);
#pragma unroll
    for (int ks = 0; ks < 2; ks++) {
      half8v whi = *(const half8v*)(wqm + (((mt * 4 + ks * 2 + 0) * 64) + lane) * 8);
      half8v wlo = *(const half8v*)(wqm + (((mt * 4 + ks * 2 + 1) * 64) + lane) * 8);
      a0 = __builtin_amdgcn_mfma_f32_16x16x32_f16(whi, xhi[s][ks], a0, 0, 0, 0);
      a0 = __builtin_amdgcn_mfma_f32_16x16x32_f16(whi, xlo[s][ks], a0, 0, 0, 0);
      a0 = __builtin_amdgcn_mfma_f32_16x16x32_f16(wlo, xhi[s][ks], a0, 0, 0, 0);
    }
    __builtin_amdgcn_s_setprio(0);
#pragma unroll
    for (int r = 0; r < 4; r++) {
      const int row = mt * 16 + lg * 4 + r;
      float v0 = softplus_(a0[r] + bqm[row]);
      const int px = w * 16 + l15;
      qL[row * 128 + ((((px >> 2) ^ (row & 7))) << 2) + (px & 3)] = v0;
    }
  }
  __syncthreads();
  // ---- phase B: fused norm + out = G.(q*rn) + bo ----
  const _Float16* gm = (const _Float16*)(ws + WS_GM) + (size_t)b * 8192;
  const int px = w * 16 + l15;
  half8v qhi[2], qlo[2];
#pragma unroll
  for (int ks = 0; ks < 2; ks++) {
    const int h = ks * 4 + lg;
    const float* ksep = ws + WS_KSE + (b * 8 + h) * 8;
    float4 kse0 = *(const float4*)ksep;
    float4 kse1 = *(const float4*)(ksep + 4);
    const float kk[8] = {kse0.x, kse0.y, kse0.z, kse0.w, kse1.x, kse1.y, kse1.z, kse1.w};
    float qv[8];
    float s = 0.0f;
#pragma unroll
    for (int j = 0; j < 8; j++) {
      const int row = ks * 32 + lg * 8 + j;      // row & 7 == j; head h rows
      qv[j] = qL[row * 128 + ((((px >> 2) ^ j)) << 2) + (px & 3)];
      s = fmaf(qv[j], kk[j], s);
    }
    const float rn4k = (1.0f / s) * 4096.0f;
#pragma unroll
    for (int j = 0; j < 8; j++) {
      _Float16 h16, l16; split_h(qv[j] * rn4k, h16, l16);
      qhi[ks][j] = h16; qlo[ks][j] = l16;
    }
  }
  f32x4v acc[4];
#pragma unroll
  for (int mt2 = 0; mt2 < 4; mt2++) acc[mt2] = (f32x4v){0.f, 0.f, 0.f, 0.f};
#pragma unroll
  for (int mt2 = 0; mt2 < 4; mt2++) {
    __builtin_amdgcn_s_setprio(1);
#pragma unroll
    for (int ks = 0; ks < 2; ks++) {
      half8v ghi = *(const half8v*)(gm + (size_t)((mt2 * 4 + ks * 2 + 0) * 64 + lane) * 8);
      half8v glo = *(const half8v*)(gm + (size_t)((mt2 * 4 + ks * 2 + 1) * 64 + lane) * 8);
      acc[mt2] = __builtin_amdgcn_mfma_f32_16x16x32_f16(ghi, qhi[ks], acc[mt2], 0, 0, 0);
      acc[mt2] = __builtin_amdgcn_mfma_f32_16x16x32_f16(ghi, qlo[ks], acc[mt2], 0, 0, 0);
      acc[mt2] = __builtin_amdgcn_mfma_f32_16x16x32_f16(glo, qhi[ks], acc[mt2], 0, 0, 0);
    }
    __builtin_amdgcn_s_setprio(0);
  }
  float* ob = out + ((size_t)b * 64) * NPIX + chunk * KPX + px;
#pragma unroll
  for (int mt2 = 0; mt2 < 4; mt2++)
#pragma unroll
    for (int r = 0; r < 4; r++) {
      const int o = mt2 * 16 + lg * 4 + r;
      ob[(size_t)o * NPIX] = acc[mt2][r] * 0.000244140625f + bo[o];
    }
}

extern "C" void kernel_launch(void* const* d_in, const int* in_sizes, int n_in,
                              void* d_out, int out_size, void* d_ws, size_t ws_size,
                              hipStream_t stream) {
  const float* high    = (const float*)d_in[0];
  const float* low     = (const float*)d_in[1];
  const float* wq_high = (const float*)d_in[2];
  const float* bq_high = (const float*)d_in[3];
  const float* wq_low  = (const float*)d_in[4];
  const float* bq_low  = (const float*)d_in[5];
  const float* wk      = (const float*)d_in[6];
  const float* bk      = (const float*)d_in[7];
  const float* wv      = (const float*)d_in[8];
  const float* bv      = (const float*)d_in[9];
  const float* wo      = (const float*)d_in[10];
  const float* bo      = (const float*)d_in[11];
  float* ws  = (float*)d_ws;
  float* out = (float*)d_out;

  k0_pack<<<1, 256, 0, stream>>>(wq_high, bq_high, wq_low, bq_low, wk, bk, wv, bv, ws);
  dim3 grid(NCH, NB);
  k1_kv<<<grid, 512, 0, stream>>>(low, ws, ws + WS_PART);
  k2_g<<<64, 256, 0, stream>>>(ws + WS_PART, wo, ws);
  k3_main<<<grid, 512, 0, stream>>>(high, low, ws, bo, out);
}

// Round 24
// 106.414 us; speedup vs baseline: 1.0279x; 1.0279x over previous
//
#include <hip/hip_runtime.h>

// MCA linear attention. B=8, C=64, H=W=160, P=8 heads, d=8, N=25600.
// MFMA on f16 split pairs (fp32-accurate). R21 structure (best measured,
// 106.6us) + k3 norm folded into phase B ONLY (R23's regression attributed
// to setprio on a barrier-locked structure -- removed everywhere).
#define NPIX  25600
#define NB    8
#define NCH   200    // pixel chunks per batch (128 px each)
#define KPX   128
#define EPSV  1e-6f

// workspace layout (float offsets)
#define WS_WQM   0        // Wq A-frags: 16 frags x 64 lanes x 8 f16
#define WS_BQM   4096     // [64 row] bias
#define WS_WKVM  4160     // Wkv A-frags: 32 frags x 512 f16-pairs
#define WS_BKVM  12352    // [8 mt][16 row] bias
#define WS_KSE   12480    // [8 b][8 p][8 m] (+eps)
#define WS_PART  12992    // [64 bh][200 ch][72]
#define WS_GM    934592   // G A-frags: 8 b x 16 frags x 512 f16

typedef __attribute__((ext_vector_type(8))) _Float16 half8v;
typedef __attribute__((ext_vector_type(4))) float f32x4v;

__device__ __forceinline__ void split_h(float x, _Float16& hi, _Float16& lo) {
  hi = (_Float16)x;                  // v_cvt_f16_f32 (RNE)
  lo = (_Float16)(x - (float)hi);    // residual, fp32-equivalent pair
}
__device__ __forceinline__ float softplus_(float x) {
  return (x > 20.0f) ? x : __logf(1.0f + __expf(x));
}

// ---------------- kernel 0: pack weight MFMA fragments (f16 pairs) ---------
__global__ void k0_pack(const float* __restrict__ wq_high, const float* __restrict__ bq_high,
                        const float* __restrict__ wq_low,  const float* __restrict__ bq_low,
                        const float* __restrict__ wk, const float* __restrict__ bk,
                        const float* __restrict__ wv, const float* __restrict__ bv,
                        float* __restrict__ ws) {
  const int tid = threadIdx.x;
  _Float16* wqm = (_Float16*)(ws + WS_WQM);
  for (int e = tid; e < 8192; e += 256) {
    int j = e & 7, l = (e >> 3) & 63, frag = e >> 9;
    int sp = frag & 1, ks = (frag >> 1) & 1, mt = frag >> 2;
    int row = mt * 16 + (l & 15), c = ks * 32 + (l >> 4) * 8 + j;
    int head = row >> 3, m = row & 7;
    float v = (head < 4) ? wq_high[(head * 8 + m) * 64 + c]
                         : wq_low[((head - 4) * 8 + m) * 64 + c];
    _Float16 hi, lo; split_h(v, hi, lo);
    wqm[e] = (sp == 0) ? hi : lo;
  }
  for (int e = tid; e < 64; e += 256) {
    int head = e >> 3, m = e & 7;
    ws[WS_BQM + e] = (head < 4) ? bq_high[head * 8 + m] : bq_low[(head - 4) * 8 + m];
  }
  _Float16* wmp = (_Float16*)(ws + WS_WKVM);
  for (int e = tid; e < 16384; e += 256) {
    int j = e & 7, l = (e >> 3) & 63, frag = e >> 9;
    int sp = frag & 1, ks = (frag >> 1) & 1, mt = frag >> 2;
    int row = l & 15, k32 = (l >> 4) * 8 + j, c = ks * 32 + k32;
    int head = (mt & 3) * 2 + (row >> 3), m = row & 7;
    float wv_ = (mt < 4) ? wk[(head * 8 + m) * 64 + c] : wv[(head * 8 + m) * 64 + c];
    _Float16 hi, lo; split_h(wv_, hi, lo);
    wmp[e] = (sp == 0) ? hi : lo;
  }
  for (int e = tid; e < 128; e += 256) {
    int mt = e >> 4, row = e & 15;
    int head = (mt & 3) * 2 + (row >> 3), m = row & 7;
    ws[WS_BKVM + e] = (mt < 4) ? bk[head * 8 + m] : bv[head * 8 + m];
  }
}

// ---------------- kernel 1: MFMA k,v + attn partials (R21 exact) -----------
// 512 thr = 8 waves; wave w owns px strip [16w,16w+16). GEMM1 -> split f16
// hi/lo LDS planes (64KB, 16B-unit XOR swizzle). GEMM2 reads frags directly.
__global__ __attribute__((amdgpu_waves_per_eu(1, 8)))
void k1_kv(const float* __restrict__ low,
           const float* __restrict__ ws,
           float* __restrict__ part) {
  const int b = blockIdx.y, chunk = blockIdx.x;
  const int tid = threadIdx.x, lane = tid & 63;
  const int w = __builtin_amdgcn_readfirstlane(tid >> 6);
  const int l15 = lane & 15, lg = lane >> 4;
  __shared__ _Float16 kvP[2][16384];             // hi/lo planes, [128r][128px]
  const float* lowb = low + (size_t)b * 64 * NPIX + chunk * KPX;
  // ---- X B-frags (f16 split) ----
  half8v xhi[2], xlo[2];
#pragma unroll
  for (int ks = 0; ks < 2; ks++) {
    const float* xp = lowb + (size_t)(ks * 32 + lg * 8) * NPIX + w * 16 + l15;
    float xs[8];
#pragma unroll
    for (int j = 0; j < 8; j++) xs[j] = xp[(size_t)j * NPIX];
#pragma unroll
    for (int j = 0; j < 8; j++) { _Float16 h, l; split_h(xs[j], h, l); xhi[ks][j] = h; xlo[ks][j] = l; }
  }
  const _Float16* wm = (const _Float16*)(ws + WS_WKVM);
  const float* bm = ws + WS_BKVM;
  // ---- GEMM1 ----
#pragma unroll
  for (int mt = 0; mt < 8; mt++) {
    f32x4v a0 = {0.f, 0.f, 0.f, 0.f};
#pragma unroll
    for (int ks = 0; ks < 2; ks++) {
      half8v whi = *(const half8v*)(wm + (((mt * 4 + ks * 2 + 0) * 64) + lane) * 8);
      half8v wlo = *(const half8v*)(wm + (((mt * 4 + ks * 2 + 1) * 64) + lane) * 8);
      a0 = __builtin_amdgcn_mfma_f32_16x16x32_f16(whi, xhi[ks], a0, 0, 0, 0);
      a0 = __builtin_amdgcn_mfma_f32_16x16x32_f16(whi, xlo[ks], a0, 0, 0, 0);
      a0 = __builtin_amdgcn_mfma_f32_16x16x32_f16(wlo, xhi[ks], a0, 0, 0, 0);
    }
#pragma unroll
    for (int r = 0; r < 4; r++) {
      const int row = mt * 16 + lg * 4 + r;
      float v0 = a0[r] + bm[row];
      if (mt < 4) v0 = softplus_(v0);
      const int px = w * 16 + l15;
      const int idx = row * 128 + ((((px >> 3) ^ (row & 7)) << 3) | (px & 7));
      _Float16 hi, lo; split_h(v0, hi, lo);
      kvP[0][idx] = hi;
      kvP[1][idx] = lo;
    }
  }
  __syncthreads();
  // ---- GEMM2: wave w -> head w; frags read directly from planes ----
  const int col = l15;
  const int h = w;
  f32x4v acc = {0.f, 0.f, 0.f, 0.f};
  const int arow = h * 8 + (l15 & 7);
  const int brow = 64 + h * 8 + (col < 8 ? col : 0);
#pragma unroll
  for (int ks = 0; ks < 4; ks++) {
    const int unitA = (((ks * 4 + lg) ^ (arow & 7)) << 3);
    const int unitB = (((ks * 4 + lg) ^ (brow & 7)) << 3);
    half8v ahi = *(const half8v*)&kvP[0][arow * 128 + unitA];
    half8v alo = *(const half8v*)&kvP[1][arow * 128 + unitA];
    half8v bhi = *(const half8v*)&kvP[0][brow * 128 + unitB];
    half8v blo = *(const half8v*)&kvP[1][brow * 128 + unitB];
    if (col >= 8) {
      const _Float16 fh = (col == 8) ? (_Float16)1.0f : (_Float16)0.0f;
#pragma unroll
      for (int j = 0; j < 8; j++) { bhi[j] = fh; blo[j] = (_Float16)0.0f; }
    }
    acc = __builtin_amdgcn_mfma_f32_16x16x32_f16(ahi, bhi, acc, 0, 0, 0);
    acc = __builtin_amdgcn_mfma_f32_16x16x32_f16(ahi, blo, acc, 0, 0, 0);
    acc = __builtin_amdgcn_mfma_f32_16x16x32_f16(alo, bhi, acc, 0, 0, 0);
  }
  if (lane < 32 && col <= 8) {
    float* pb = part + ((size_t)(b * 8 + h) * NCH + chunk) * 72;
#pragma unroll
    for (int r = 0; r < 4; r++) {
      const int rr = lg * 4 + r;
      if (col < 8) pb[rr * 8 + col] = acc[r];
      else         pb[64 + rr] = acc[r];
    }
  }
}

// ---------------- kernel 2: reduce partials, ksumE, G f16 frags ------------
__global__ void k2_g(const float* __restrict__ part, const float* __restrict__ wo,
                     float* __restrict__ ws) {
  const int b = blockIdx.x >> 3, p = blockIdx.x & 7;
  const int tid = threadIdx.x, lane = tid & 63, sub = tid >> 6;
  __shared__ float red[4][72];
  __shared__ float attnL[72];
  const float* src = part + (size_t)(b * 8 + p) * NCH * 72;
  float s0 = 0.0f, s1 = 0.0f;
  for (int ch = sub * (NCH / 4); ch < (sub + 1) * (NCH / 4); ch++) {
    s0 += src[ch * 72 + lane];
    if (lane < 8) s1 += src[ch * 72 + 64 + lane];
  }
  red[sub][lane] = s0;
  if (lane < 8) red[sub][64 + lane] = s1;
  __syncthreads();
  if (tid < 72) attnL[tid] = (red[0][tid] + red[1][tid]) + (red[2][tid] + red[3][tid]);
  __syncthreads();
  if (tid >= 64) {
    if (tid < 72) ws[WS_KSE + (b * 8 + p) * 8 + (tid - 64)] = attnL[tid] + EPSV;
    return;
  }
  const int o = tid;
  float wrow[8];
#pragma unroll
  for (int c = 0; c < 8; c++) wrow[c] = wo[o * 64 + p * 8 + c];
  _Float16* gm = (_Float16*)(ws + WS_GM) + (size_t)b * 8192;
  const int mt2 = o >> 4, lane_ = (p & 3) * 16 + (o & 15), ks = p >> 2;
  half8v hi8, lo8;
#pragma unroll
  for (int m = 0; m < 8; m++) {
    float g = 0.0f;
#pragma unroll
    for (int c = 0; c < 8; c++) g = fmaf(attnL[m * 8 + c], wrow[c], g);
    _Float16 hi, lo; split_h(g, hi, lo);
    hi8[m] = hi; lo8[m] = lo;
  }
  *(half8v*)(gm + (size_t)((mt2 * 4 + ks * 2 + 0) * 64 + lane_) * 8) = hi8;
  *(half8v*)(gm + (size_t)((mt2 * 4 + ks * 2 + 1) * 64 + lane_) * 8) = lo8;
}

// ---------------- kernel 3: MFMA q -> fused norm+out-projection ------------
// 512 thr = 8 waves, strip [16w,16w+16). Phase A -> fp32 qL (32KB swizzled).
// Phase B: lane reads head (ks*4+lg)'s 8 q-rows at its px (needed for the
// B-frag anyway) -> computes s, rn INLINE (norm phase + rnL + one barrier
// deleted). No setprio (R23: negative on barrier-locked structure).
// qsn scaled x4096 to dodge f16 subnormals; unscaled in epilogue.
__global__ __attribute__((amdgpu_waves_per_eu(1, 8)))
void k3_main(const float* __restrict__ high,
             const float* __restrict__ low,
             const float* __restrict__ ws,
             const float* __restrict__ bo,
             float* __restrict__ out) {
  const int b = blockIdx.y, chunk = blockIdx.x;
  const int tid = threadIdx.x, lane = tid & 63;
  const int w = __builtin_amdgcn_readfirstlane(tid >> 6);
  const int l15 = lane & 15, lg = lane >> 4;
  __shared__ float qL[8192];                     // [64 row][128 px] swizzled
  const float* highb = high + (size_t)b * 64 * NPIX + chunk * KPX;
  const float* lowb  = low  + (size_t)b * 64 * NPIX + chunk * KPX;
  // ---- X B-frags (both sources, f16 split) ----
  half8v xhi[2][2], xlo[2][2];                   // [src][ks]
#pragma unroll
  for (int s = 0; s < 2; s++) {
    const float* srcb = (s == 0) ? highb : lowb;
#pragma unroll
    for (int ks = 0; ks < 2; ks++) {
      const float* xp = srcb + (size_t)(ks * 32 + lg * 8) * NPIX + w * 16 + l15;
      float xs[8];
#pragma unroll
      for (int j = 0; j < 8; j++) xs[j] = xp[(size_t)j * NPIX];
#pragma unroll
      for (int j = 0; j < 8; j++) { _Float16 h, l; split_h(xs[j], h, l); xhi[s][ks][j] = h; xlo[s][ks][j] = l; }
    }
  }
  const _Float16* wqm = (const _Float16*)(ws + WS_WQM);
  const float* bqm = ws + WS_BQM;
  // ---- phase A ----
#pragma unroll
  for (int mt = 0; mt < 4; mt++) {
    const int s = mt >> 1;
    f32x4v a0 = {0.f, 0.f, 0.f, 0.f};
#pragma unroll
    for (int ks = 0; ks < 2; ks++) {
      half8v whi = *(const half8v*)(wqm + (((mt * 4 + ks * 2 + 0) * 64) + lane) * 8);
      half8v wlo = *(const half8v*)(wqm + (((mt * 4 + ks * 2 + 1) * 64) + lane) * 8);
      a0 = __builtin_amdgcn_mfma_f32_16x16x32_f16(whi, xhi[s][ks], a0, 0, 0, 0);
      a0 = __builtin_amdgcn_mfma_f32_16x16x32_f16(whi, xlo[s][ks], a0, 0, 0, 0);
      a0 = __builtin_amdgcn_mfma_f32_16x16x32_f16(wlo, xhi[s][ks], a0, 0, 0, 0);
    }
#pragma unroll
    for (int r = 0; r < 4; r++) {
      const int row = mt * 16 + lg * 4 + r;
      float v0 = softplus_(a0[r] + bqm[row]);
      const int px = w * 16 + l15;
      qL[row * 128 + ((((px >> 2) ^ (row & 7))) << 2) + (px & 3)] = v0;
    }
  }
  __syncthreads();
  // ---- phase B: fused norm + out = G.(q*rn) + bo ----
  const _Float16* gm = (const _Float16*)(ws + WS_GM) + (size_t)b * 8192;
  const int px = w * 16 + l15;
  half8v qhi[2], qlo[2];
#pragma unroll
  for (int ks = 0; ks < 2; ks++) {
    const int h = ks * 4 + lg;
    const float* ksep = ws + WS_KSE + (b * 8 + h) * 8;
    float4 kse0 = *(const float4*)ksep;
    float4 kse1 = *(const float4*)(ksep + 4);
    const float kk[8] = {kse0.x, kse0.y, kse0.z, kse0.w, kse1.x, kse1.y, kse1.z, kse1.w};
    float qv[8];
    float s = 0.0f;
#pragma unroll
    for (int j = 0; j < 8; j++) {
      const int row = ks * 32 + lg * 8 + j;      // row & 7 == j; head h rows
      qv[j] = qL[row * 128 + ((((px >> 2) ^ j)) << 2) + (px & 3)];
      s = fmaf(qv[j], kk[j], s);
    }
    const float rn4k = (1.0f / s) * 4096.0f;
#pragma unroll
    for (int j = 0; j < 8; j++) {
      _Float16 h16, l16; split_h(qv[j] * rn4k, h16, l16);
      qhi[ks][j] = h16; qlo[ks][j] = l16;
    }
  }
  f32x4v acc[4];
#pragma unroll
  for (int mt2 = 0; mt2 < 4; mt2++) acc[mt2] = (f32x4v){0.f, 0.f, 0.f, 0.f};
#pragma unroll
  for (int mt2 = 0; mt2 < 4; mt2++) {
#pragma unroll
    for (int ks = 0; ks < 2; ks++) {
      half8v ghi = *(const half8v*)(gm + (size_t)((mt2 * 4 + ks * 2 + 0) * 64 + lane) * 8);
      half8v glo = *(const half8v*)(gm + (size_t)((mt2 * 4 + ks * 2 + 1) * 64 + lane) * 8);
      acc[mt2] = __builtin_amdgcn_mfma_f32_16x16x32_f16(ghi, qhi[ks], acc[mt2], 0, 0, 0);
      acc[mt2] = __builtin_amdgcn_mfma_f32_16x16x32_f16(ghi, qlo[ks], acc[mt2], 0, 0, 0);
      acc[mt2] = __builtin_amdgcn_mfma_f32_16x16x32_f16(glo, qhi[ks], acc[mt2], 0, 0, 0);
    }
  }
  float* ob = out + ((size_t)b * 64) * NPIX + chunk * KPX + px;
#pragma unroll
  for (int mt2 = 0; mt2 < 4; mt2++)
#pragma unroll
    for (int r = 0; r < 4; r++) {
      const int o = mt2 * 16 + lg * 4 + r;
      ob[(size_t)o * NPIX] = acc[mt2][r] * 0.000244140625f + bo[o];
    }
}

extern "C" void kernel_launch(void* const* d_in, const int* in_sizes, int n_in,
                              void* d_out, int out_size, void* d_ws, size_t ws_size,
                              hipStream_t stream) {
  const float* high    = (const float*)d_in[0];
  const float* low     = (const float*)d_in[1];
  const float* wq_high = (const float*)d_in[2];
  const float* bq_high = (const float*)d_in[3];
  const float* wq_low  = (const float*)d_in[4];
  const float* bq_low  = (const float*)d_in[5];
  const float* wk      = (const float*)d_in[6];
  const float* bk      = (const float*)d_in[7];
  const float* wv      = (const float*)d_in[8];
  const float* bv      = (const float*)d_in[9];
  const float* wo      = (const float*)d_in[10];
  const float* bo      = (const float*)d_in[11];
  float* ws  = (float*)d_ws;
  float* out = (float*)d_out;

  k0_pack<<<1, 256, 0, stream>>>(wq_high, bq_high, wq_low, bq_low, wk, bk, wv, bv, ws);
  dim3 grid(NCH, NB);
  k1_kv<<<grid, 512, 0, stream>>>(low, ws, ws + WS_PART);
  k2_g<<<64, 256, 0, stream>>>(ws + WS_PART, wo, ws);
  k3_main<<<grid, 512, 0, stream>>>(high, low, ws, bo, out);
}